// Round 7
// baseline (478.858 us; speedup 1.0000x reference)
//
#include <hip/hip_runtime.h>

#define NB 4
#define NC 64
#define MID 16
#define NH 4
#define KS 7
#define PAD 3
#define HH 128
#define WW 128
#define TILE 16
#define HALO (TILE + KS - 1)      /* 22 */
#define NCELL (HALO * HALO)       /* 484 */
#define PLANE (HH * WW)

// ---------------- QKV: three 64x64 GEMMs over 65536 pixels, fp32 ----------------
// block = 256 threads, blockIdx.y = matrix (Q/K/V), blockIdx.x = 256-pixel tile.
// W^T staged once in LDS (broadcast b128 reads); x staged in double-buffered
// 16-row chunks with register prefetch. Thread tile: 8 outputs x 8 pixels.
__global__ __launch_bounds__(256) void qkv_kernel(
    const float* __restrict__ x,
    const float* __restrict__ Wq, const float* __restrict__ bq,
    const float* __restrict__ Wk, const float* __restrict__ bk,
    const float* __restrict__ Wv, const float* __restrict__ bv,
    float* __restrict__ Qm, float* __restrict__ Km, float* __restrict__ Vm)
{
    __shared__ float wt[NC][68];        // W^T [c][o], +4 pad keeps b128 alignment
    __shared__ float xt[2][16][256];    // x chunk [k][pixel], double-buffered
    __shared__ float bias_s[NC];

    const int t = threadIdx.x;
    const int m = blockIdx.y;
    const float* Wm = (m == 0) ? Wq : (m == 1) ? Wk : Wv;
    const float* bm = (m == 0) ? bq : (m == 1) ? bk : bv;
    float*       Om = (m == 0) ? Qm : (m == 1) ? Km : Vm;

    const int tile = blockIdx.x;            // 0..255
    const int b    = tile >> 6;             // 64 tiles per image
    const int hw0  = (tile & 63) << 8;      // *256
    const float* xb = x + ((size_t)b * NC) * PLANE + hw0;

    // stage W^T + bias (one-time)
    #pragma unroll
    for (int r = 0; r < 16; ++r) {
        const int idx = (r << 8) + t;       // 0..4095, coalesced read of W[o][c]
        wt[idx & 63][idx >> 6] = Wm[idx];
    }
    if (t < NC) bias_s[t] = bm[t];

    // stage chunk 0 (rows 0..15)
    #pragma unroll
    for (int r = 0; r < 4; ++r) {
        const int idx = (r << 8) + t;       // 0..1023
        const int row = idx >> 6;
        const int c4  = idx & 63;
        ((float4*)&xt[0][row][0])[c4] =
            ((const float4*)(xb + (size_t)row * PLANE))[c4];
    }
    __syncthreads();

    const int o0 = (t >> 5) << 3;           // 8 output-groups of 8
    const int p0 = t & 31;                  // pixel set {p0 + 32j}
    float acc[8][8];
    #pragma unroll
    for (int i = 0; i < 8; ++i)
        #pragma unroll
        for (int j = 0; j < 8; ++j) acc[i][j] = 0.f;

    for (int ck = 0; ck < 4; ++ck) {
        const int buf = ck & 1;
        float4 pre[4];
        if (ck < 3) {                       // prefetch next chunk into regs
            #pragma unroll
            for (int r = 0; r < 4; ++r) {
                const int idx = (r << 8) + t;
                pre[r] = ((const float4*)(xb + (size_t)((ck + 1) * 16 + (idx >> 6)) * PLANE))[idx & 63];
            }
        }
        #pragma unroll
        for (int kk = 0; kk < 16; ++kk) {
            const int c = (ck << 4) + kk;
            const float4 wa = *(const float4*)&wt[c][o0];
            const float4 wb = *(const float4*)&wt[c][o0 + 4];
            const float w8[8] = {wa.x, wa.y, wa.z, wa.w, wb.x, wb.y, wb.z, wb.w};
            float x8[8];
            #pragma unroll
            for (int j = 0; j < 8; ++j) x8[j] = xt[buf][kk][p0 + (j << 5)];
            #pragma unroll
            for (int i = 0; i < 8; ++i)
                #pragma unroll
                for (int j = 0; j < 8; ++j)
                    acc[i][j] = fmaf(w8[i], x8[j], acc[i][j]);
        }
        if (ck < 3) {                       // write prefetched chunk to other buffer
            #pragma unroll
            for (int r = 0; r < 4; ++r) {
                const int idx = (r << 8) + t;
                ((float4*)&xt[buf ^ 1][idx >> 6][0])[idx & 63] = pre[r];
            }
        }
        __syncthreads();
    }

    float* ob = Om + ((size_t)b * NC) * PLANE + hw0;
    #pragma unroll
    for (int i = 0; i < 8; ++i) {
        const float bi = bias_s[o0 + i];
        #pragma unroll
        for (int j = 0; j < 8; ++j)
            ob[(size_t)(o0 + i) * PLANE + p0 + (j << 5)] = acc[i][j] + bi;
    }
}

// ---------------- neighborhood attention, 2-pass, vectorized LDS ----------------
// LDS layout: T[cell][16ch] fp32, 16B-unit XOR swizzle (unit ^= cell&3) ->
// conflict-free ds_read_b128, alignment preserved. One 31KB buffer: K for
// pass 1 (scores -> wgt[49] regs), then V for pass 2.
__global__ __launch_bounds__(256) void attn_kernel(
    const float* __restrict__ x,
    const float* __restrict__ Qm, const float* __restrict__ Km,
    const float* __restrict__ Vm, float* __restrict__ out)
{
    __shared__ float T[NCELL * MID];    // 484*16*4B = 31KB

    int blk = blockIdx.x;
    const int tx0 = (blk & 7) * TILE; blk >>= 3;
    const int ty0 = (blk & 7) * TILE; blk >>= 3;
    const int g   = blk & 3;
    const int b   = blk >> 2;

    const int t  = threadIdx.x;
    const int tx = t & 15, ty = t >> 4;

    const float* Kb = Km + ((size_t)b * NC + g * MID) * PLANE;
    const float* Vb = Vm + ((size_t)b * NC + g * MID) * PLANE;

    const size_t pbase = ((size_t)b * NC + g * MID) * PLANE
                       + (size_t)(ty0 + ty) * WW + (tx0 + tx);

    // issue q loads early (overlap with K staging)
    float q[MID];
    #pragma unroll
    for (int c = 0; c < MID; ++c) q[c] = Qm[pbase + (size_t)c * PLANE];

    // stage with swizzle: dword = cell*16 + ((c>>2)^(cell&3))*4 + (c&3)
    auto stage = [&](const float* base) {
        for (int i = t; i < NCELL; i += 256) {
            const int yy = i / HALO, xx = i - yy * HALO;
            const int h = ty0 + yy - PAD, w = tx0 + xx - PAD;
            const bool in = (h >= 0) & (h < HH) & (w >= 0) & (w < WW);
            const int cb = i << 4;
            const int sw = i & 3;
            #pragma unroll
            for (int c = 0; c < MID; ++c) {
                float v = 0.f;
                if (in) v = base[(size_t)c * PLANE + h * WW + w];
                T[cb + ((((c >> 2) ^ sw)) << 2) + (c & 3)] = v;
            }
        }
    };

    stage(Kb);
    __syncthreads();

    float wgt[KS * KS];
    float l = 0.f;
    // pass 1: scores + exp (OOB taps: K=0 -> s=0 -> exp=1, matches zero-padded unfold)
    #pragma unroll
    for (int kh = 0; kh < KS; ++kh) {
        #pragma unroll
        for (int kw = 0; kw < KS; ++kw) {
            const int cell = (ty + kh) * HALO + (tx + kw);
            const int cb = cell << 4;
            const int sw = cell & 3;
            float s = 0.f;
            #pragma unroll
            for (int u = 0; u < 4; ++u) {
                const float4 k4 = *(const float4*)&T[cb + ((u ^ sw) << 2)];
                s = fmaf(q[u * 4 + 0], k4.x, s);
                s = fmaf(q[u * 4 + 1], k4.y, s);
                s = fmaf(q[u * 4 + 2], k4.z, s);
                s = fmaf(q[u * 4 + 3], k4.w, s);
            }
            const float e = __expf(s);      // |s| bounded ~25, safe fp32
            wgt[kh * KS + kw] = e;
            l += e;
        }
    }
    __syncthreads();
    stage(Vb);
    __syncthreads();

    float acc[MID];
    #pragma unroll
    for (int c = 0; c < MID; ++c) acc[c] = 0.f;

    // pass 2: weighted V accumulate
    #pragma unroll
    for (int kh = 0; kh < KS; ++kh) {
        #pragma unroll
        for (int kw = 0; kw < KS; ++kw) {
            const int cell = (ty + kh) * HALO + (tx + kw);
            const int cb = cell << 4;
            const int sw = cell & 3;
            const float e = wgt[kh * KS + kw];
            #pragma unroll
            for (int u = 0; u < 4; ++u) {
                const float4 v4 = *(const float4*)&T[cb + ((u ^ sw) << 2)];
                acc[u * 4 + 0] = fmaf(e, v4.x, acc[u * 4 + 0]);
                acc[u * 4 + 1] = fmaf(e, v4.y, acc[u * 4 + 1]);
                acc[u * 4 + 2] = fmaf(e, v4.z, acc[u * 4 + 2]);
                acc[u * 4 + 3] = fmaf(e, v4.w, acc[u * 4 + 3]);
            }
        }
    }

    const float inv = 1.f / l;
    #pragma unroll
    for (int c = 0; c < MID; ++c) {
        const size_t idx = pbase + (size_t)c * PLANE;
        out[idx] = x[idx] + acc[c] * inv;
    }
}

extern "C" void kernel_launch(void* const* d_in, const int* in_sizes, int n_in,
                              void* d_out, int out_size, void* d_ws, size_t ws_size,
                              hipStream_t stream) {
    const float* x  = (const float*)d_in[0];
    const float* Wq = (const float*)d_in[1];
    const float* bq = (const float*)d_in[2];
    const float* Wk = (const float*)d_in[3];
    const float* bk = (const float*)d_in[4];
    const float* Wv = (const float*)d_in[5];
    const float* bv = (const float*)d_in[6];
    float* out = (float*)d_out;

    const size_t map_elems = (size_t)NB * NC * PLANE;
    float* Qm = (float*)d_ws;
    float* Km = Qm + map_elems;
    float* Vm = Km + map_elems;

    dim3 g1(256, 3);     // 256 pixel-tiles x {Q,K,V}
    qkv_kernel<<<g1, 256, 0, stream>>>(x, Wq, bq, Wk, bk, Wv, bv, Qm, Km, Vm);

    const int nblk = NB * NH * (HH / TILE) * (WW / TILE);   // 1024
    attn_kernel<<<nblk, 256, 0, stream>>>(x, Qm, Km, Vm, out);
}

// Round 9
// 169.180 us; speedup vs baseline: 2.8305x; 2.8305x over previous
//
#include <hip/hip_runtime.h>

#define NB 4
#define NC 64
#define MID 16
#define NH 4
#define KS 7
#define PAD 3
#define HH 128
#define WW 128
#define TILE 16
#define HALO (TILE + KS - 1)      /* 22 */
#define NCELL (HALO * HALO)       /* 484 */
#define PLANE (HH * WW)

// ---------------- QKV: three 64x64 GEMMs over 65536 pixels, fp32 ----------------
// (unchanged from round 7 — dropped out of top-5, ~15-40us)
__global__ __launch_bounds__(256) void qkv_kernel(
    const float* __restrict__ x,
    const float* __restrict__ Wq, const float* __restrict__ bq,
    const float* __restrict__ Wk, const float* __restrict__ bk,
    const float* __restrict__ Wv, const float* __restrict__ bv,
    float* __restrict__ Qm, float* __restrict__ Km, float* __restrict__ Vm)
{
    __shared__ float wt[NC][68];
    __shared__ float xt[2][16][256];
    __shared__ float bias_s[NC];

    const int t = threadIdx.x;
    const int m = blockIdx.y;
    const float* Wm = (m == 0) ? Wq : (m == 1) ? Wk : Wv;
    const float* bm = (m == 0) ? bq : (m == 1) ? bk : bv;
    float*       Om = (m == 0) ? Qm : (m == 1) ? Km : Vm;

    const int tile = blockIdx.x;
    const int b    = tile >> 6;
    const int hw0  = (tile & 63) << 8;
    const float* xb = x + ((size_t)b * NC) * PLANE + hw0;

    #pragma unroll
    for (int r = 0; r < 16; ++r) {
        const int idx = (r << 8) + t;
        wt[idx & 63][idx >> 6] = Wm[idx];
    }
    if (t < NC) bias_s[t] = bm[t];

    #pragma unroll
    for (int r = 0; r < 4; ++r) {
        const int idx = (r << 8) + t;
        ((float4*)&xt[0][idx >> 6][0])[idx & 63] =
            ((const float4*)(xb + (size_t)(idx >> 6) * PLANE))[idx & 63];
    }
    __syncthreads();

    const int o0 = (t >> 5) << 3;
    const int p0 = t & 31;
    float acc[8][8];
    #pragma unroll
    for (int i = 0; i < 8; ++i)
        #pragma unroll
        for (int j = 0; j < 8; ++j) acc[i][j] = 0.f;

    for (int ck = 0; ck < 4; ++ck) {
        const int buf = ck & 1;
        float4 pre[4];
        if (ck < 3) {
            #pragma unroll
            for (int r = 0; r < 4; ++r) {
                const int idx = (r << 8) + t;
                pre[r] = ((const float4*)(xb + (size_t)((ck + 1) * 16 + (idx >> 6)) * PLANE))[idx & 63];
            }
        }
        #pragma unroll
        for (int kk = 0; kk < 16; ++kk) {
            const int c = (ck << 4) + kk;
            const float4 wa = *(const float4*)&wt[c][o0];
            const float4 wb = *(const float4*)&wt[c][o0 + 4];
            const float w8[8] = {wa.x, wa.y, wa.z, wa.w, wb.x, wb.y, wb.z, wb.w};
            float x8[8];
            #pragma unroll
            for (int j = 0; j < 8; ++j) x8[j] = xt[buf][kk][p0 + (j << 5)];
            #pragma unroll
            for (int i = 0; i < 8; ++i)
                #pragma unroll
                for (int j = 0; j < 8; ++j)
                    acc[i][j] = fmaf(w8[i], x8[j], acc[i][j]);
        }
        if (ck < 3) {
            #pragma unroll
            for (int r = 0; r < 4; ++r) {
                const int idx = (r << 8) + t;
                ((float4*)&xt[buf ^ 1][idx >> 6][0])[idx & 63] = pre[r];
            }
        }
        __syncthreads();
    }

    float* ob = Om + ((size_t)b * NC) * PLANE + hw0;
    #pragma unroll
    for (int i = 0; i < 8; ++i) {
        const float bi = bias_s[o0 + i];
        #pragma unroll
        for (int j = 0; j < 8; ++j)
            ob[(size_t)(o0 + i) * PLANE + p0 + (j << 5)] = acc[i][j] + bi;
    }
}

// ---------------- neighborhood attention, SINGLE-pass, swizzled cell-major ------
// K and V both staged (2x31KB). No wgt[] array -> no spills. LDS dword address:
//   cell*16 + ((u ^ ((cell>>1)&3)) << 2) + (c&3)   (u = c>>2)
// Quad-group = 4*(cell&1) + (u^((cell>>1)&3)): balanced 8 lanes/quad for BOTH
// the linear b128 staging writes and the 64-lane tap reads -> conflict-free.
__global__ __launch_bounds__(256) void attn_kernel(
    const float* __restrict__ x,
    const float* __restrict__ Qm, const float* __restrict__ Km,
    const float* __restrict__ Vm, float* __restrict__ out)
{
    __shared__ float Kt[NCELL * MID];   // 31KB
    __shared__ float Vt[NCELL * MID];   // 31KB

    int blk = blockIdx.x;
    const int tx0 = (blk & 7) * TILE; blk >>= 3;
    const int ty0 = (blk & 7) * TILE; blk >>= 3;
    const int g   = blk & 3;
    const int b   = blk >> 2;

    const int t  = threadIdx.x;
    const int tx = t & 15, ty = t >> 4;

    const float* Kb = Km + ((size_t)b * NC + g * MID) * PLANE;
    const float* Vb = Vm + ((size_t)b * NC + g * MID) * PLANE;

    const size_t pbase = ((size_t)b * NC + g * MID) * PLANE
                       + (size_t)(ty0 + ty) * WW + (tx0 + tx);

    // q early (overlaps staging)
    float q[MID];
    #pragma unroll
    for (int c = 0; c < MID; ++c) q[c] = Qm[pbase + c * PLANE];

    // stage: thread handles (cell, u) units; gathers 4 channels -> one b128 write
    auto stage = [&](const float* base, float* T) {
        for (int i = t; i < NCELL * 4; i += 256) {
            const int cell = i >> 2;
            const int u    = i & 3;
            const int yy = cell / HALO, xx = cell - yy * HALO;
            const int h = ty0 + yy - PAD, w = tx0 + xx - PAD;
            float4 v = make_float4(0.f, 0.f, 0.f, 0.f);
            if ((h >= 0) & (h < HH) & (w >= 0) & (w < WW)) {
                const float* src = base + (size_t)(u * 4) * PLANE + h * WW + w;
                v.x = src[0];
                v.y = src[PLANE];
                v.z = src[2 * PLANE];
                v.w = src[3 * PLANE];
            }
            *(float4*)&T[(cell << 4) + ((u ^ ((cell >> 1) & 3)) << 2)] = v;
        }
    };
    stage(Kb, Kt);
    stage(Vb, Vt);
    __syncthreads();

    float l = 0.f;
    float acc[MID];
    #pragma unroll
    for (int c = 0; c < MID; ++c) acc[c] = 0.f;

    for (int kh = 0; kh < KS; ++kh) {
        const int rowc = (ty + kh) * HALO + tx;
        #pragma unroll
        for (int kw = 0; kw < KS; ++kw) {
            const int cell = rowc + kw;
            const int cb = cell << 4;
            const int sw = (cell >> 1) & 3;
            // 4 partial sums for ILP
            float s0 = 0.f, s1 = 0.f, s2 = 0.f, s3 = 0.f;
            {
                const float4 k0 = *(const float4*)&Kt[cb + ((0 ^ sw) << 2)];
                const float4 k1 = *(const float4*)&Kt[cb + ((1 ^ sw) << 2)];
                const float4 k2 = *(const float4*)&Kt[cb + ((2 ^ sw) << 2)];
                const float4 k3 = *(const float4*)&Kt[cb + ((3 ^ sw) << 2)];
                s0 = fmaf(q[0],  k0.x, fmaf(q[1],  k0.y, fmaf(q[2],  k0.z, q[3]  * k0.w)));
                s1 = fmaf(q[4],  k1.x, fmaf(q[5],  k1.y, fmaf(q[6],  k1.z, q[7]  * k1.w)));
                s2 = fmaf(q[8],  k2.x, fmaf(q[9],  k2.y, fmaf(q[10], k2.z, q[11] * k2.w)));
                s3 = fmaf(q[12], k3.x, fmaf(q[13], k3.y, fmaf(q[14], k3.z, q[15] * k3.w)));
            }
            const float e = __expf((s0 + s1) + (s2 + s3));  // OOB: K=0 -> e=1, matches unfold
            l += e;
            #pragma unroll
            for (int u = 0; u < 4; ++u) {
                const float4 v4 = *(const float4*)&Vt[cb + ((u ^ sw) << 2)];
                acc[4 * u + 0] = fmaf(e, v4.x, acc[4 * u + 0]);
                acc[4 * u + 1] = fmaf(e, v4.y, acc[4 * u + 1]);
                acc[4 * u + 2] = fmaf(e, v4.z, acc[4 * u + 2]);
                acc[4 * u + 3] = fmaf(e, v4.w, acc[4 * u + 3]);
            }
        }
    }

    const float inv = 1.f / l;
    #pragma unroll
    for (int c = 0; c < MID; ++c) {
        const size_t idx = pbase + c * PLANE;
        out[idx] = x[idx] + acc[c] * inv;
    }
}

extern "C" void kernel_launch(void* const* d_in, const int* in_sizes, int n_in,
                              void* d_out, int out_size, void* d_ws, size_t ws_size,
                              hipStream_t stream) {
    const float* x  = (const float*)d_in[0];
    const float* Wq = (const float*)d_in[1];
    const float* bq = (const float*)d_in[2];
    const float* Wk = (const float*)d_in[3];
    const float* bk = (const float*)d_in[4];
    const float* Wv = (const float*)d_in[5];
    const float* bv = (const float*)d_in[6];
    float* out = (float*)d_out;

    const size_t map_elems = (size_t)NB * NC * PLANE;
    float* Qm = (float*)d_ws;
    float* Km = Qm + map_elems;
    float* Vm = Km + map_elems;

    dim3 g1(256, 3);
    qkv_kernel<<<g1, 256, 0, stream>>>(x, Wq, bq, Wk, bk, Wv, bv, Qm, Km, Vm);

    const int nblk = NB * NH * (HH / TILE) * (WW / TILE);   // 1024
    attn_kernel<<<nblk, 256, 0, stream>>>(x, Qm, Km, Vm, out);
}

// Round 10
// 158.942 us; speedup vs baseline: 3.0128x; 1.0644x over previous
//
#include <hip/hip_runtime.h>

#define NB 4
#define NC 64
#define MID 16
#define NH 4
#define KS 7
#define PAD 3
#define HH 128
#define WW 128
#define TILE 16
#define HALO (TILE + KS - 1)      /* 22 */
#define NCELL (HALO * HALO)       /* 484 */
#define PLANE (HH * WW)

typedef _Float16 h2 __attribute__((ext_vector_type(2)));
typedef _Float16 h4 __attribute__((ext_vector_type(4)));
typedef _Float16 h8 __attribute__((ext_vector_type(8)));

__device__ __forceinline__ h2 pack2(float x, float y) {
    h2 r; r[0] = (_Float16)x; r[1] = (_Float16)y; return r;
}

#if __has_builtin(__builtin_amdgcn_fdot2)
#define FDOT2(a, b, c) __builtin_amdgcn_fdot2((a), (b), (c), false)
#else
__device__ __forceinline__ float FDOT2(h2 a, h2 b, float c) {
    return fmaf((float)a[0], (float)b[0], fmaf((float)a[1], (float)b[1], c));
}
#endif

#define H2OF(v, j) __builtin_shufflevector((v), (v), 2*(j), 2*(j)+1)

// ---------------- QKV: three 64x64 GEMMs over 65536 pixels, fp32 ----------------
// change vs r9: thread pixel-tile = 4+4 consecutive pixels -> x reads are
// 2x ds_read_b128 (was 8x ds_read_b32), stores are float4.
__global__ __launch_bounds__(256) void qkv_kernel(
    const float* __restrict__ x,
    const float* __restrict__ Wq, const float* __restrict__ bq,
    const float* __restrict__ Wk, const float* __restrict__ bk,
    const float* __restrict__ Wv, const float* __restrict__ bv,
    float* __restrict__ Qm, float* __restrict__ Km, float* __restrict__ Vm)
{
    __shared__ float wt[NC][68];
    __shared__ float xt[2][16][256];
    __shared__ float bias_s[NC];

    const int t = threadIdx.x;
    const int m = blockIdx.y;
    const float* Wm = (m == 0) ? Wq : (m == 1) ? Wk : Wv;
    const float* bm = (m == 0) ? bq : (m == 1) ? bk : bv;
    float*       Om = (m == 0) ? Qm : (m == 1) ? Km : Vm;

    const int tile = blockIdx.x;
    const int b    = tile >> 6;
    const int hw0  = (tile & 63) << 8;
    const float* xb = x + ((size_t)b * NC) * PLANE + hw0;

    #pragma unroll
    for (int r = 0; r < 16; ++r) {
        const int idx = (r << 8) + t;
        wt[idx & 63][idx >> 6] = Wm[idx];
    }
    if (t < NC) bias_s[t] = bm[t];

    #pragma unroll
    for (int r = 0; r < 4; ++r) {
        const int idx = (r << 8) + t;
        ((float4*)&xt[0][idx >> 6][0])[idx & 63] =
            ((const float4*)(xb + (size_t)(idx >> 6) * PLANE))[idx & 63];
    }
    __syncthreads();

    const int o0  = (t >> 5) << 3;
    const int q04 = (t & 31) << 2;      // 4 consecutive pixels; +128 for 2nd group
    float acc[8][8];
    #pragma unroll
    for (int i = 0; i < 8; ++i)
        #pragma unroll
        for (int j = 0; j < 8; ++j) acc[i][j] = 0.f;

    for (int ck = 0; ck < 4; ++ck) {
        const int buf = ck & 1;
        float4 pre[4];
        if (ck < 3) {
            #pragma unroll
            for (int r = 0; r < 4; ++r) {
                const int idx = (r << 8) + t;
                pre[r] = ((const float4*)(xb + (size_t)((ck + 1) * 16 + (idx >> 6)) * PLANE))[idx & 63];
            }
        }
        #pragma unroll
        for (int kk = 0; kk < 16; ++kk) {
            const int c = (ck << 4) + kk;
            const float4 wa = *(const float4*)&wt[c][o0];
            const float4 wb = *(const float4*)&wt[c][o0 + 4];
            const float w8[8] = {wa.x, wa.y, wa.z, wa.w, wb.x, wb.y, wb.z, wb.w};
            const float4 xa = *(const float4*)&xt[buf][kk][q04];
            const float4 xc = *(const float4*)&xt[buf][kk][q04 + 128];
            const float x8[8] = {xa.x, xa.y, xa.z, xa.w, xc.x, xc.y, xc.z, xc.w};
            #pragma unroll
            for (int i = 0; i < 8; ++i)
                #pragma unroll
                for (int j = 0; j < 8; ++j)
                    acc[i][j] = fmaf(w8[i], x8[j], acc[i][j]);
        }
        if (ck < 3) {
            #pragma unroll
            for (int r = 0; r < 4; ++r) {
                const int idx = (r << 8) + t;
                ((float4*)&xt[buf ^ 1][idx >> 6][0])[idx & 63] = pre[r];
            }
        }
        __syncthreads();
    }

    float* ob = Om + ((size_t)b * NC) * PLANE + hw0;
    #pragma unroll
    for (int i = 0; i < 8; ++i) {
        const float bi = bias_s[o0 + i];
        float* orow = ob + (size_t)(o0 + i) * PLANE;
        float4 s0 = {acc[i][0] + bi, acc[i][1] + bi, acc[i][2] + bi, acc[i][3] + bi};
        float4 s1 = {acc[i][4] + bi, acc[i][5] + bi, acc[i][6] + bi, acc[i][7] + bi};
        *(float4*)&orow[q04]       = s0;
        *(float4*)&orow[q04 + 128] = s1;
    }
}

// ---------------- neighborhood attention, single-pass, f16 K/V in LDS ----------
// Per cell: 16 f16 = 32B = 8 dwords. Cell stride 8 dwords => mod-4 cell class
// selects a distinct 8-bank group: both b64 staging writes and b128 tap reads
// are at the bank floor with NO swizzle. K-dot via v_dot2_f32_f16.
__global__ __launch_bounds__(256) void attn_kernel(
    const float* __restrict__ x,
    const float* __restrict__ Qm, const float* __restrict__ Km,
    const float* __restrict__ Vm, float* __restrict__ out)
{
    __shared__ _Float16 Kt[NCELL * 16];   // 15.5KB
    __shared__ _Float16 Vt[NCELL * 16];   // 15.5KB

    int blk = blockIdx.x;
    const int tx0 = (blk & 7) * TILE; blk >>= 3;
    const int ty0 = (blk & 7) * TILE; blk >>= 3;
    const int g   = blk & 3;
    const int b   = blk >> 2;

    const int t  = threadIdx.x;
    const int tx = t & 15, ty = t >> 4;

    const float* Kb = Km + ((size_t)b * NC + g * MID) * PLANE;
    const float* Vb = Vm + ((size_t)b * NC + g * MID) * PLANE;

    const size_t pbase = ((size_t)b * NC + g * MID) * PLANE
                       + (size_t)(ty0 + ty) * WW + (tx0 + tx);

    // q early (overlaps staging), converted to f16 pairs
    h2 qh[8];
    #pragma unroll
    for (int c = 0; c < 8; ++c)
        qh[c] = pack2(Qm[pbase + (2 * c) * PLANE], Qm[pbase + (2 * c + 1) * PLANE]);

    // stage: thread handles (cell,u); gathers 4 channels -> one 8B f16 store
    auto stage = [&](const float* base, _Float16* T) {
        for (int i = t; i < NCELL * 4; i += 256) {
            const int cell = i >> 2;
            const int u    = i & 3;
            const int yy = cell / HALO, xx = cell - yy * HALO;
            const int h = ty0 + yy - PAD, w = tx0 + xx - PAD;
            float4 v = make_float4(0.f, 0.f, 0.f, 0.f);
            if ((h >= 0) & (h < HH) & (w >= 0) & (w < WW)) {
                const float* src = base + (size_t)(u * 4) * PLANE + h * WW + w;
                v.x = src[0];
                v.y = src[PLANE];
                v.z = src[2 * PLANE];
                v.w = src[3 * PLANE];
            }
            h4 hv;
            hv[0] = (_Float16)v.x; hv[1] = (_Float16)v.y;
            hv[2] = (_Float16)v.z; hv[3] = (_Float16)v.w;
            *(h4*)&T[(cell << 4) + (u << 2)] = hv;
        }
    };
    stage(Kb, Kt);
    stage(Vb, Vt);
    __syncthreads();

    float l = 0.f;
    float acc[MID];
    #pragma unroll
    for (int c = 0; c < MID; ++c) acc[c] = 0.f;

    for (int kh = 0; kh < KS; ++kh) {
        const int rowc = (ty + kh) * HALO + tx;
        #pragma unroll
        for (int kw = 0; kw < KS; ++kw) {
            const int cb = (rowc + kw) << 4;
            const h8 k0 = *(const h8*)&Kt[cb];
            const h8 k1 = *(const h8*)&Kt[cb + 8];
            // two independent dot chains
            float sa = FDOT2(H2OF(k0, 0), qh[0], 0.f);
            float sb = FDOT2(H2OF(k1, 0), qh[4], 0.f);
            sa = FDOT2(H2OF(k0, 1), qh[1], sa);
            sb = FDOT2(H2OF(k1, 1), qh[5], sb);
            sa = FDOT2(H2OF(k0, 2), qh[2], sa);
            sb = FDOT2(H2OF(k1, 2), qh[6], sb);
            sa = FDOT2(H2OF(k0, 3), qh[3], sa);
            sb = FDOT2(H2OF(k1, 3), qh[7], sb);
            const float e = __expf(sa + sb);   // OOB: K=0 -> e=1, matches unfold
            l += e;
            const h8 v0 = *(const h8*)&Vt[cb];
            const h8 v1 = *(const h8*)&Vt[cb + 8];
            #pragma unroll
            for (int j = 0; j < 8; ++j)
                acc[j] = fmaf(e, (float)v0[j], acc[j]);
            #pragma unroll
            for (int j = 0; j < 8; ++j)
                acc[8 + j] = fmaf(e, (float)v1[j], acc[8 + j]);
        }
    }

    const float inv = 1.f / l;
    #pragma unroll
    for (int c = 0; c < MID; ++c) {
        const size_t idx = pbase + c * PLANE;
        out[idx] = x[idx] + acc[c] * inv;
    }
}

extern "C" void kernel_launch(void* const* d_in, const int* in_sizes, int n_in,
                              void* d_out, int out_size, void* d_ws, size_t ws_size,
                              hipStream_t stream) {
    const float* x  = (const float*)d_in[0];
    const float* Wq = (const float*)d_in[1];
    const float* bq = (const float*)d_in[2];
    const float* Wk = (const float*)d_in[3];
    const float* bk = (const float*)d_in[4];
    const float* Wv = (const float*)d_in[5];
    const float* bv = (const float*)d_in[6];
    float* out = (float*)d_out;

    const size_t map_elems = (size_t)NB * NC * PLANE;
    float* Qm = (float*)d_ws;
    float* Km = Qm + map_elems;
    float* Vm = Km + map_elems;

    dim3 g1(256, 3);
    qkv_kernel<<<g1, 256, 0, stream>>>(x, Wq, bq, Wk, bk, Wv, bv, Qm, Km, Vm);

    const int nblk = NB * NH * (HH / TILE) * (WW / TILE);   // 1024
    attn_kernel<<<nblk, 256, 0, stream>>>(x, Qm, Km, Vm, out);
}

// Round 11
// 143.569 us; speedup vs baseline: 3.3354x; 1.1071x over previous
//
#include <hip/hip_runtime.h>

#define NB 4
#define NC 64
#define MID 16
#define NH 4
#define KS 7
#define PAD 3
#define HH 128
#define WW 128
#define TILE 16
#define HALO (TILE + KS - 1)      /* 22 */
#define NCELL (HALO * HALO)       /* 484 */
#define PLANE (HH * WW)

typedef _Float16 h2 __attribute__((ext_vector_type(2)));
typedef _Float16 h4 __attribute__((ext_vector_type(4)));
typedef _Float16 h8 __attribute__((ext_vector_type(8)));

__device__ __forceinline__ h2 pack2(float x, float y) {
    h2 r; r[0] = (_Float16)x; r[1] = (_Float16)y; return r;
}

#if __has_builtin(__builtin_amdgcn_fdot2)
#define FDOT2(a, b, c) __builtin_amdgcn_fdot2((a), (b), (c), false)
#else
__device__ __forceinline__ float FDOT2(h2 a, h2 b, float c) {
    return fmaf((float)a[0], (float)b[0], fmaf((float)a[1], (float)b[1], c));
}
#endif

#define H2OF(v, j) __builtin_shufflevector((v), (v), 2*(j), 2*(j)+1)

// ---------------- QKV: three 64x64 GEMMs over 65536 pixels, fp32 ----------------
// r11: occupancy + broadcast-w restructure. 512 thr / 128-px tile / 1536 blocks.
// o0 = wave*8 (wave-uniform) -> w-reads are same-address broadcast b128.
// Thread tile 8 out x 2 px -> acc 16 regs, target <64 VGPR -> 8 waves/SIMD.
__global__ __launch_bounds__(512) void qkv_kernel(
    const float* __restrict__ x,
    const float* __restrict__ Wq, const float* __restrict__ bq,
    const float* __restrict__ Wk, const float* __restrict__ bk,
    const float* __restrict__ Wv, const float* __restrict__ bv,
    float* __restrict__ Qm, float* __restrict__ Km, float* __restrict__ Vm)
{
    __shared__ float wt[NC][68];        // W^T [c][o]
    __shared__ float xt[2][16][128];    // x chunk [k][pixel], double-buffered
    __shared__ float bias_s[NC];

    const int t = threadIdx.x;
    const int m = blockIdx.y;
    const float* Wm = (m == 0) ? Wq : (m == 1) ? Wk : Wv;
    const float* bm = (m == 0) ? bq : (m == 1) ? bk : bv;
    float*       Om = (m == 0) ? Qm : (m == 1) ? Km : Vm;

    const int tile = blockIdx.x;            // 0..511
    const int b    = tile >> 7;             // 128 tiles per image
    const int hw0  = (tile & 127) << 7;     // *128
    const float* xb = x + ((size_t)b * NC) * PLANE + hw0;

    // stage W^T (coalesced) + bias
    #pragma unroll
    for (int r = 0; r < 8; ++r) {
        const int idx = (r << 9) + t;       // 0..4095, W[o][c] row-major
        wt[idx & 63][idx >> 6] = Wm[idx];
    }
    if (t < NC) bias_s[t] = bm[t];

    const int row = t >> 5;                 // 0..15
    const int c4  = t & 31;
    // stage chunk 0 (rows 0..15): 512 float4, one per thread
    ((float4*)&xt[0][row][0])[c4] =
        ((const float4*)(xb + (size_t)row * PLANE))[c4];
    __syncthreads();

    const int o0    = (t >> 6) << 3;        // wave-uniform: 8 waves x 8 outs
    const int lane2 = (t & 63) << 1;        // 2 consecutive pixels
    float acc[8][2];
    #pragma unroll
    for (int i = 0; i < 8; ++i) { acc[i][0] = 0.f; acc[i][1] = 0.f; }

    for (int ck = 0; ck < 4; ++ck) {
        const int buf = ck & 1;
        float4 pre;
        if (ck < 3)
            pre = ((const float4*)(xb + (size_t)((ck + 1) * 16 + row) * PLANE))[c4];
        #pragma unroll
        for (int kk = 0; kk < 16; ++kk) {
            const int c = (ck << 4) + kk;
            const float4 wa = *(const float4*)&wt[c][o0];       // broadcast
            const float4 wb = *(const float4*)&wt[c][o0 + 4];   // broadcast
            const float w8[8] = {wa.x, wa.y, wa.z, wa.w, wb.x, wb.y, wb.z, wb.w};
            const float2 x2 = *(const float2*)&xt[buf][kk][lane2];
            #pragma unroll
            for (int i = 0; i < 8; ++i) {
                acc[i][0] = fmaf(w8[i], x2.x, acc[i][0]);
                acc[i][1] = fmaf(w8[i], x2.y, acc[i][1]);
            }
        }
        if (ck < 3)
            ((float4*)&xt[buf ^ 1][row][0])[c4] = pre;
        __syncthreads();
    }

    float* ob = Om + ((size_t)b * NC) * PLANE + hw0;
    #pragma unroll
    for (int i = 0; i < 8; ++i) {
        float2 s = {acc[i][0] + bias_s[o0 + i], acc[i][1] + bias_s[o0 + i]};
        *(float2*)&ob[(size_t)(o0 + i) * PLANE + lane2] = s;
    }
}

// ---------------- neighborhood attention, single-pass, f16 K/V in LDS ----------
// (unchanged from round 10: 159us run, attn < 48us)
__global__ __launch_bounds__(256) void attn_kernel(
    const float* __restrict__ x,
    const float* __restrict__ Qm, const float* __restrict__ Km,
    const float* __restrict__ Vm, float* __restrict__ out)
{
    __shared__ _Float16 Kt[NCELL * 16];   // 15.5KB
    __shared__ _Float16 Vt[NCELL * 16];   // 15.5KB

    int blk = blockIdx.x;
    const int tx0 = (blk & 7) * TILE; blk >>= 3;
    const int ty0 = (blk & 7) * TILE; blk >>= 3;
    const int g   = blk & 3;
    const int b   = blk >> 2;

    const int t  = threadIdx.x;
    const int tx = t & 15, ty = t >> 4;

    const float* Kb = Km + ((size_t)b * NC + g * MID) * PLANE;
    const float* Vb = Vm + ((size_t)b * NC + g * MID) * PLANE;

    const size_t pbase = ((size_t)b * NC + g * MID) * PLANE
                       + (size_t)(ty0 + ty) * WW + (tx0 + tx);

    // q early (overlaps staging), converted to f16 pairs
    h2 qh[8];
    #pragma unroll
    for (int c = 0; c < 8; ++c)
        qh[c] = pack2(Qm[pbase + (2 * c) * PLANE], Qm[pbase + (2 * c + 1) * PLANE]);

    // stage: thread handles (cell,u); gathers 4 channels -> one 8B f16 store
    auto stage = [&](const float* base, _Float16* T) {
        for (int i = t; i < NCELL * 4; i += 256) {
            const int cell = i >> 2;
            const int u    = i & 3;
            const int yy = cell / HALO, xx = cell - yy * HALO;
            const int h = ty0 + yy - PAD, w = tx0 + xx - PAD;
            float4 v = make_float4(0.f, 0.f, 0.f, 0.f);
            if ((h >= 0) & (h < HH) & (w >= 0) & (w < WW)) {
                const float* src = base + (size_t)(u * 4) * PLANE + h * WW + w;
                v.x = src[0];
                v.y = src[PLANE];
                v.z = src[2 * PLANE];
                v.w = src[3 * PLANE];
            }
            h4 hv;
            hv[0] = (_Float16)v.x; hv[1] = (_Float16)v.y;
            hv[2] = (_Float16)v.z; hv[3] = (_Float16)v.w;
            *(h4*)&T[(cell << 4) + (u << 2)] = hv;
        }
    };
    stage(Kb, Kt);
    stage(Vb, Vt);
    __syncthreads();

    float l = 0.f;
    float acc[MID];
    #pragma unroll
    for (int c = 0; c < MID; ++c) acc[c] = 0.f;

    for (int kh = 0; kh < KS; ++kh) {
        const int rowc = (ty + kh) * HALO + tx;
        #pragma unroll
        for (int kw = 0; kw < KS; ++kw) {
            const int cb = (rowc + kw) << 4;
            const h8 k0 = *(const h8*)&Kt[cb];
            const h8 k1 = *(const h8*)&Kt[cb + 8];
            // two independent dot chains
            float sa = FDOT2(H2OF(k0, 0), qh[0], 0.f);
            float sb = FDOT2(H2OF(k1, 0), qh[4], 0.f);
            sa = FDOT2(H2OF(k0, 1), qh[1], sa);
            sb = FDOT2(H2OF(k1, 1), qh[5], sb);
            sa = FDOT2(H2OF(k0, 2), qh[2], sa);
            sb = FDOT2(H2OF(k1, 2), qh[6], sb);
            sa = FDOT2(H2OF(k0, 3), qh[3], sa);
            sb = FDOT2(H2OF(k1, 3), qh[7], sb);
            const float e = __expf(sa + sb);   // OOB: K=0 -> e=1, matches unfold
            l += e;
            const h8 v0 = *(const h8*)&Vt[cb];
            const h8 v1 = *(const h8*)&Vt[cb + 8];
            #pragma unroll
            for (int j = 0; j < 8; ++j)
                acc[j] = fmaf(e, (float)v0[j], acc[j]);
            #pragma unroll
            for (int j = 0; j < 8; ++j)
                acc[8 + j] = fmaf(e, (float)v1[j], acc[8 + j]);
        }
    }

    const float inv = 1.f / l;
    #pragma unroll
    for (int c = 0; c < MID; ++c) {
        const size_t idx = pbase + c * PLANE;
        out[idx] = x[idx] + acc[c] * inv;
    }
}

extern "C" void kernel_launch(void* const* d_in, const int* in_sizes, int n_in,
                              void* d_out, int out_size, void* d_ws, size_t ws_size,
                              hipStream_t stream) {
    const float* x  = (const float*)d_in[0];
    const float* Wq = (const float*)d_in[1];
    const float* bq = (const float*)d_in[2];
    const float* Wk = (const float*)d_in[3];
    const float* bk = (const float*)d_in[4];
    const float* Wv = (const float*)d_in[5];
    const float* bv = (const float*)d_in[6];
    float* out = (float*)d_out;

    const size_t map_elems = (size_t)NB * NC * PLANE;
    float* Qm = (float*)d_ws;
    float* Km = Qm + map_elems;
    float* Vm = Km + map_elems;

    dim3 g1(512, 3);     // 512 pixel-tiles x {Q,K,V}
    qkv_kernel<<<g1, 512, 0, stream>>>(x, Wq, bq, Wk, bk, Wv, bv, Qm, Km, Vm);

    const int nblk = NB * NH * (HH / TILE) * (WW / TILE);   // 1024
    attn_kernel<<<nblk, 256, 0, stream>>>(x, Qm, Km, Vm, out);
}